// Round 1
// baseline (608.053 us; speedup 1.0000x reference)
//
#include <hip/hip_runtime.h>

// GRU stack (L=6, H=2048, batch=1) + LayerNorm + Linear head. ALL fp32.
// Memory-bound on ~621 MB fp32 weights (~99 us roofline at 6.3 TB/s).
//
// R1 theory: previous version (604 us) was latency*occupancy bound:
//   ~128 VGPR -> 12 waves/CU, 8 float4 loads in flight/wave = 1.5 KB/CU
//   -> ~1.7 B/cyc/CU = 1.03 TB/s. Fix: global_load_lds staging (in-flight
//   bytes cost zero VGPRs), counted vmcnt(4) double-buffered 4KB halves,
//   8 KB in flight per wave continuously. Predict ~17-22 us/layer.

constexpr int HID = 2048;
constexpr int NL  = 6;
constexpr int G3  = 3 * HID;   // 6144 gate rows per layer

__device__ __forceinline__ float wave_sum(float s){
  #pragma unroll
  for(int off = 32; off; off >>= 1) s += __shfl_down(s, off, 64);
  return s;  // lane 0 holds total
}

// async 16B/lane global->LDS: one instr moves 1 KB (64 lanes x 16 B).
// LDS dest is wave-uniform base + lane*16 (linear), global src is per-lane.
__device__ __forceinline__ void gls16(const void* g, void* l){
  __builtin_amdgcn_global_load_lds(
      (const __attribute__((address_space(1))) void*)g,
      (__attribute__((address_space(3))) void*)l,
      16, 0, 0);
}

// stage one 4 KB half-row (1024 floats) as 4 x 1KB chunks
__device__ __forceinline__ void stage_half(float4* dst, const float* rowbase,
                                           int hf, int lane){
  const char* g = (const char*)rowbase + hf * 4096 + lane * 16;
  char* l = (char*)dst;
  #pragma unroll
  for(int c = 0; c < 4; ++c) gls16(g + c * 1024, l + c * 1024);
}

// Block = 256 thr = 4 waves; wave w owns output j = blockIdx*4 + w and
// streams its 6 gate rows (3x w_ih, 3x w_hh) through a 2x4KB LDS window.
// Steady state per wave: 8 gls outstanding (8 KB); s_waitcnt vmcnt(4)
// releases the current half while the next half stays in flight.
__global__ __launch_bounds__(256) void k_layer(
    const float* __restrict__ w_ih_l,
    const float* __restrict__ w_hh_l,
    const float* __restrict__ b_ih_l,
    const float* __restrict__ b_hh_l,
    const float* __restrict__ h_l,
    const float* __restrict__ inp,
    float* __restrict__ h_new_ws,   // feeds next layer
    float* __restrict__ h_new_out)  // new_hidden output slot
{
  __shared__ float4 stg[4][2][256];  // per-wave double buffer, 32 KB
  __shared__ float4 vvs[2][512];     // [0]=inp, [1]=h, 16 KB  (48 KB total)

  const int wave = threadIdx.x >> 6;
  const int lane = threadIdx.x & 63;
  const int j    = blockIdx.x * 4 + wave;

  const float* rp[6] = {
    w_ih_l + (size_t)(0 * HID + j) * HID,
    w_ih_l + (size_t)(1 * HID + j) * HID,
    w_ih_l + (size_t)(2 * HID + j) * HID,
    w_hh_l + (size_t)(0 * HID + j) * HID,
    w_hh_l + (size_t)(1 * HID + j) * HID,
    w_hh_l + (size_t)(2 * HID + j) * HID };

  // --- prologue: 4 vector gls (wave w stages chunks 2w,2w+1 of inp and h),
  // then halves H0,H1 of row 0.  outstanding = 12.
  {
    const int c0 = wave * 2;
    gls16((const char*)inp + (c0    ) * 1024 + lane * 16, (char*)&vvs[0][0] + (c0    ) * 1024);
    gls16((const char*)inp + (c0 + 1) * 1024 + lane * 16, (char*)&vvs[0][0] + (c0 + 1) * 1024);
    gls16((const char*)h_l + (c0    ) * 1024 + lane * 16, (char*)&vvs[1][0] + (c0    ) * 1024);
    gls16((const char*)h_l + (c0 + 1) * 1024 + lane * 16, (char*)&vvs[1][0] + (c0 + 1) * 1024);
  }
  stage_half(&stg[wave][0][0], rp[0], 0, lane);
  stage_half(&stg[wave][1][0], rp[0], 1, lane);
  asm volatile("s_waitcnt vmcnt(8)" ::: "memory");  // 4 oldest (vectors) done
  __builtin_amdgcn_sched_barrier(0);
  __syncthreads();                                  // all waves' vectors staged

  // --- main pipeline over 12 halves (6 rows x 2).  H_k lives in buf k&1.
  float acc[6] = {0.f, 0.f, 0.f, 0.f, 0.f, 0.f};
  #pragma unroll
  for(int k = 0; k < 12; ++k){
    if(k < 11) { asm volatile("s_waitcnt vmcnt(4)" ::: "memory"); }
    else       { asm volatile("s_waitcnt vmcnt(0)" ::: "memory"); }
    __builtin_amdgcn_sched_barrier(0);
    const float4* w = &stg[wave][k & 1][0];
    const float4* v = ((k >> 1) < 3) ? &vvs[0][(k & 1) * 256]
                                     : &vvs[1][(k & 1) * 256];
    float s = 0.f;
    #pragma unroll
    for(int c = 0; c < 4; ++c){
      float4 a = w[c * 64 + lane];
      float4 b = v[c * 64 + lane];
      s += a.x * b.x + a.y * b.y + a.z * b.z + a.w * b.w;
    }
    acc[k >> 1] += s;
    if(k < 10){
      // buffer k&1 fully consumed; drain ds_reads, then refill with H_{k+2}
      asm volatile("s_waitcnt lgkmcnt(0)" ::: "memory");
      stage_half(&stg[wave][k & 1][0], rp[(k + 2) >> 1], (k + 2) & 1, lane);
    }
  }

  const float g0 = wave_sum(acc[0]);
  const float g1 = wave_sum(acc[1]);
  const float g2 = wave_sum(acc[2]);
  const float g3 = wave_sum(acc[3]);
  const float g4 = wave_sum(acc[4]);
  const float g5 = wave_sum(acc[5]);

  if(lane == 0){
    float gi_r = g0 + b_ih_l[j];
    float gi_z = g1 + b_ih_l[HID + j];
    float gi_n = g2 + b_ih_l[2 * HID + j];
    float gh_r = g3 + b_hh_l[j];
    float gh_z = g4 + b_hh_l[HID + j];
    float gh_n = g5 + b_hh_l[2 * HID + j];
    float r = 1.f / (1.f + __expf(-(gi_r + gh_r)));
    float z = 1.f / (1.f + __expf(-(gi_z + gh_z)));
    float n = tanhf(gi_n + r * gh_n);
    float hn = (1.f - z) * n + z * h_l[j];
    h_new_ws[j]  = hn;
    h_new_out[j] = hn;
  }
}

__global__ __launch_bounds__(256) void k_layernorm(
    const float* __restrict__ h,
    const float* __restrict__ gamma,
    const float* __restrict__ beta,
    float* __restrict__ out)
{
  __shared__ float rs[4], rs2[4];
  __shared__ float s_mu, s_istd;
  int wave = threadIdx.x >> 6, lane = threadIdx.x & 63;
  float s = 0.f, s2 = 0.f;
  for(int i = threadIdx.x; i < HID; i += 256){ float v = h[i]; s += v; s2 += v * v; }
  #pragma unroll
  for(int off = 32; off; off >>= 1){ s += __shfl_down(s, off, 64); s2 += __shfl_down(s2, off, 64); }
  if(lane == 0){ rs[wave] = s; rs2[wave] = s2; }
  __syncthreads();
  if(threadIdx.x == 0){
    float S  = rs[0] + rs[1] + rs[2] + rs[3];
    float S2 = rs2[0] + rs2[1] + rs2[2] + rs2[3];
    float m   = S * (1.f / HID);
    float var = S2 * (1.f / HID) - m * m;
    s_mu = m; s_istd = rsqrtf(var + 1e-5f);
  }
  __syncthreads();
  float mu = s_mu, istd = s_istd;
  for(int i = threadIdx.x; i < HID; i += 256){
    out[i] = (h[i] - mu) * istd * gamma[i] + beta[i];
  }
}

// pred[o] = ln_out . lin_w[o] + lin_b[o] + x[o]; wave per output row,
// same LDS-staging structure (1 row = halves H0,H1).
__global__ __launch_bounds__(256) void k_linear(
    const float* __restrict__ v,
    const float* __restrict__ lin_w,
    const float* __restrict__ lin_b,
    const float* __restrict__ x,
    float* __restrict__ pred)
{
  __shared__ float4 stg[4][2][256];  // 32 KB
  __shared__ float4 vbs[512];        // 8 KB

  const int wave = threadIdx.x >> 6;
  const int lane = threadIdx.x & 63;
  const int o    = blockIdx.x * 4 + wave;
  const float* row = lin_w + (size_t)o * HID;

  {
    const int c0 = wave * 2;
    gls16((const char*)v + (c0    ) * 1024 + lane * 16, (char*)&vbs[0] + (c0    ) * 1024);
    gls16((const char*)v + (c0 + 1) * 1024 + lane * 16, (char*)&vbs[0] + (c0 + 1) * 1024);
  }
  stage_half(&stg[wave][0][0], row, 0, lane);
  stage_half(&stg[wave][1][0], row, 1, lane);
  asm volatile("s_waitcnt vmcnt(8)" ::: "memory");  // 2 oldest (vector) done
  __builtin_amdgcn_sched_barrier(0);
  __syncthreads();

  float acc = 0.f;
  #pragma unroll
  for(int k = 0; k < 2; ++k){
    if(k == 0) { asm volatile("s_waitcnt vmcnt(4)" ::: "memory"); }
    else       { asm volatile("s_waitcnt vmcnt(0)" ::: "memory"); }
    __builtin_amdgcn_sched_barrier(0);
    const float4* w = &stg[wave][k][0];
    const float4* vb = &vbs[k * 256];
    float s = 0.f;
    #pragma unroll
    for(int c = 0; c < 4; ++c){
      float4 a = w[c * 64 + lane];
      float4 b = vb[c * 64 + lane];
      s += a.x * b.x + a.y * b.y + a.z * b.z + a.w * b.w;
    }
    acc += s;
  }
  acc = wave_sum(acc);
  if(lane == 0) pred[o] = acc + lin_b[o] + x[o];
}

extern "C" void kernel_launch(void* const* d_in, const int* in_sizes, int n_in,
                              void* d_out, int out_size, void* d_ws, size_t ws_size,
                              hipStream_t stream){
  const float* x      = (const float*)d_in[0];
  const float* hidden = (const float*)d_in[1];
  const float* w_ih   = (const float*)d_in[2];
  const float* w_hh   = (const float*)d_in[3];
  const float* b_ih   = (const float*)d_in[4];
  const float* b_hh   = (const float*)d_in[5];
  const float* gamma  = (const float*)d_in[6];
  const float* beta   = (const float*)d_in[7];
  const float* lin_w  = (const float*)d_in[8];
  const float* lin_b  = (const float*)d_in[9];
  float* out = (float*)d_out;  // [pred(2048) | new_hidden(6*2048)]

  // ws: activation chain buf[l*HID], l=0..5; ln_out at buf[6*HID]
  float* buf = (float*)d_ws;

  for(int l = 0; l < NL; ++l){
    k_layer<<<HID / 4, 256, 0, stream>>>(
        w_ih + (size_t)l * G3 * HID,
        w_hh + (size_t)l * G3 * HID,
        b_ih + (size_t)l * G3,
        b_hh + (size_t)l * G3,
        hidden + (size_t)l * HID,
        (l == 0) ? x : buf + (size_t)(l - 1) * HID,
        buf + (size_t)l * HID,
        out + HID + (size_t)l * HID);
  }
  k_layernorm<<<1, 256, 0, stream>>>(buf + 5 * HID, gamma, beta, buf + 6 * HID);
  k_linear<<<HID / 4, 256, 0, stream>>>(buf + 6 * HID, lin_w, lin_b, x, out);
}